// Round 9
// baseline (6022.389 us; speedup 1.0000x reference)
//
#include <hip/hip_runtime.h>
#include <hip/hip_bf16.h>
#include <stdint.h>

#define B_ 64
#define S_ 512
#define I_ 512
#define H_ 1024
#define NB 64              // blocks; block g owns 16 h-columns [16g, 16g+16)
#define HWORDS (B_ * H_)   // 65536 bf16 per h buffer

typedef __attribute__((ext_vector_type(8))) __bf16 bf16x8;
typedef __attribute__((ext_vector_type(4))) float f32x4;
typedef __attribute__((ext_vector_type(4))) unsigned u32x4;

__device__ __forceinline__ unsigned short f2bf(float f) {
    unsigned u = __float_as_uint(f);
    u += 0x7FFFu + ((u >> 16) & 1u);   // RNE
    return (unsigned short)(u >> 16);
}

__device__ __forceinline__ bf16x8 ld8(const unsigned short* p) {
    return *(const bf16x8*)p;
}

// ---------- prep: convert x to bf16 ----------
__global__ __launch_bounds__(256) void gru_prep(const float* __restrict__ x,
                                                unsigned short* __restrict__ xbf) {
    const int NX = (B_ * S_ * I_) / 4;
    int stride = gridDim.x * blockDim.x;
    for (int i = blockIdx.x * blockDim.x + threadIdx.x; i < NX; i += stride) {
        float4 v = ((const float4*)x)[i];
        ushort4 o;
        o.x = f2bf(v.x); o.y = f2bf(v.y); o.z = f2bf(v.z); o.w = f2bf(v.w);
        ((ushort4*)xbf)[i] = o;
    }
}

// ---------- round-14: R6 (proven, 8.3us/step) + loop rotation ----------
// Ledger (us/step): R0 12.1 | R1 11.9 | R2 15.5 | R3 12.1 | R6 8.3 PASSED |
// R7/R8 FAILED (counted-vmcnt + tag-retry + 256-reg asm arrays: wait
// arithmetic breaks under register pressure; lesson = tags only with
// monolithic vmcnt(0); counted vmcnt only with certified-before-issue).
//
// This round changes ONLY ORDER, not protocol. R6's exposed chain was:
// gates -> h-stores -> ACK vmcnt(0) [~1 RT exposed] -> flag -> poll -> data.
// Rotation: the release (ack+flag) moves AFTER the next x-phase (~1.5us of
// h-independent MFMA), so the h-stores are old when vmcnt(0) runs -> ack is
// free. Ordering invariant unchanged: stores -> vmcnt(0) -> flag. Consumer
// unchanged (poll then certified burst + counted drain, R6-proven). ABA
// unchanged: flag t+1 from block b still certifies b consumed ALL h_t
// (h_{t+1} computation needed it), so overwriting buf parity with h_{t+2}
// after poll(t+1) is safe.
//
// Per-iteration order:  A: x-phase(t)   B: release h_t (free ack + flag)
//                       C: poll flags>=t  D: h burst + counted drain + MFMA
//                       E: gates          F: store h_{t+1}, out(t) (no ack)

// 16B L2-bypassing load, literal byte offset (data certified by flag protocol)
#define LDH(dst, off) asm volatile(                                           \
    "global_load_dwordx4 %0, %1, off offset:" #off " sc0 sc1"                 \
    : "=v"(dst) : "v"(hp))

#define ISSUE_ALL() do{                                                       \
    LDH(d[0],0);     LDH(d[1],64);    LDH(d[2],128);   LDH(d[3],192);         \
    LDH(d[4],256);   LDH(d[5],320);   LDH(d[6],384);   LDH(d[7],448);         \
    LDH(d[8],512);   LDH(d[9],576);   LDH(d[10],640);  LDH(d[11],704);        \
    LDH(d[12],768);  LDH(d[13],832);  LDH(d[14],896);  LDH(d[15],960);        \
    LDH(d[16],1024); LDH(d[17],1088); LDH(d[18],1152); LDH(d[19],1216);       \
    LDH(d[20],1280); LDH(d[21],1344); LDH(d[22],1408); LDH(d[23],1472);       \
    LDH(d[24],1536); LDH(d[25],1600); LDH(d[26],1664); LDH(d[27],1728);       \
    LDH(d[28],1792); LDH(d[29],1856); LDH(d[30],1920); LDH(d[31],1984); }while(0)

#define WAITV(n) do{ asm volatile("s_waitcnt vmcnt(" #n ")" ::: "memory");    \
                     __builtin_amdgcn_sched_barrier(0); }while(0)

template<int G>
__device__ __forceinline__ void mfma_group(const u32x4* d,
        const unsigned short* wr, const unsigned short* wz, const unsigned short* wn,
        f32x4& ar, f32x4& az, f32x4& ahn) {
    #pragma unroll
    for (int kk = 0; kk < 8; ++kk) {
        const int ki = G * 8 + kk;
        union { u32x4 u; bf16x8 v; } a;
        a.u = d[ki];                       // raw bf16 fragment
        bf16x8 br = *(const bf16x8*)&wr[ki * 32];
        bf16x8 bz = *(const bf16x8*)&wz[ki * 32];
        bf16x8 bn = *(const bf16x8*)&wn[ki * 32];
        ar  = __builtin_amdgcn_mfma_f32_16x16x32_bf16(a.v, br, ar, 0, 0, 0);
        az  = __builtin_amdgcn_mfma_f32_16x16x32_bf16(a.v, bz, az, 0, 0, 0);
        ahn = __builtin_amdgcn_mfma_f32_16x16x32_bf16(a.v, bn, ahn, 0, 0, 0);
    }
}

// ---------- persistent scan ----------
// 64 blocks, block g owns h columns [16g,16g+16). 4 waves, wave w = batches
// [16w,16w+16) = exactly the rows producer-wave w of every block writes, so
// the 4 wave-planes are fully independent pipelines (no barriers in the loop).
__global__ __launch_bounds__(256, 1) void gru_scan(
    const unsigned short* __restrict__ xbf,
    const float* __restrict__ Wih,
    const float* __restrict__ mask,
    const float* __restrict__ init_h,
    const float* __restrict__ dmask,
    const float* __restrict__ Whh,
    const float* __restrict__ bih,
    const float* __restrict__ bhh,
    float* __restrict__ out,
    float* __restrict__ out_last,
    unsigned* __restrict__ flags,        // [4 planes][64 blocks] dwords, zeroed
    unsigned short* __restrict__ hbuf16) // 2 buffers of 64*1024 bf16
{
    __shared__ unsigned short wlds[48 * 1032];   // W_hh slice, rows r/z/n
    __shared__ unsigned short wxlds[48 * 520];   // W_ih slice

    const int g   = blockIdx.x;
    const int tid = threadIdx.x;
    const int w   = tid >> 6;
    const int l   = tid & 63;
    const int q   = l >> 4;          // k-quad
    const int c   = l & 15;          // n-col within block / m-row for A

    for (int idx = tid; idx < 48 * 1024; idx += 256) {
        int row = idx >> 10, col = idx & 1023;
        int sr = (row < 16) ? (g * 16 + row)
               : (row < 32) ? (H_ + g * 16 + row - 16)
                            : (2 * H_ + g * 16 + row - 32);
        wlds[row * 1032 + col] = f2bf(Whh[(size_t)sr * H_ + col]);
    }
    for (int idx = tid; idx < 48 * 512; idx += 256) {
        int row = idx >> 9, col = idx & 511;
        int sr = (row < 16) ? (g * 16 + row)
               : (row < 32) ? (H_ + g * 16 + row - 16)
                            : (2 * H_ + g * 16 + row - 32);
        wxlds[row * 520 + col] = f2bf(Wih[(size_t)sr * I_ + col]);
    }

    const int jd = g * 16 + c;
    const float b_r   = bih[jd] + bhh[jd];
    const float b_z   = bih[H_ + jd] + bhh[H_ + jd];
    const float bxn_b = bih[2 * H_ + jd];
    const float bhn_b = bhh[2 * H_ + jd];

    const int batch_A = w * 16 + c;

    float dm[4], hd[4], mc[4];
    int batch_C[4];
    #pragma unroll
    for (int r = 0; r < 4; ++r) {
        batch_C[r] = w * 16 + q * 4 + r;
        dm[r] = dmask[batch_C[r] * H_ + jd];
        float m1 = mask[batch_C[r] * S_ + 0];
        float h0 = init_h[batch_C[r] * H_ + jd];
        hd[r] = h0 * (dm[r] * m1 + 1.0f - m1);   // pre-dropped h for step 1
        mc[r] = m1;
        __hip_atomic_store(&hbuf16[HWORDS + batch_C[r] * H_ + jd], f2bf(hd[r]),
                           __ATOMIC_RELAXED, __HIP_MEMORY_SCOPE_AGENT);
    }
    // NOTE: no flag post here — the rotated loop posts flag t after x-phase(t).
    __syncthreads();   // weights staged (implicit full drain: h_1 stores acked)

    const int offx_r = c * 520,  offx_z = (16 + c) * 520,  offx_n = (32 + c) * 520;
    const unsigned short* wr = wlds + c * 1032 + q * 8;
    const unsigned short* wz = wlds + (16 + c) * 1032 + q * 8;
    const unsigned short* wn = wlds + (32 + c) * 1032 + q * 8;
    const unsigned* fp = flags + w * 64 + l;     // plane-w flag, one per lane

    for (int t = 1; t <= S_; ++t) {
        const int s = t - 1;
        f32x4 ar, az, axn, ahn;
        #pragma unroll
        for (int r = 0; r < 4; ++r) { ar[r] = b_r; az[r] = b_z; axn[r] = bxn_b; ahn[r] = bhn_b; }

        float mn[4];
        if (t < S_) {
            #pragma unroll
            for (int r = 0; r < 4; ++r) mn[r] = mask[batch_C[r] * S_ + t];
        }

        // ---- A: x phase (h-independent; hides the h_t store acks) ----
        {
            const unsigned short* xp = xbf + (size_t)batch_A * (S_ * I_) + s * I_ + q * 8;
            #pragma unroll 4
            for (int ki = 0; ki < 16; ++ki) {
                bf16x8 a  = ld8(xp + ki * 32);
                bf16x8 br = *(const bf16x8*)&wxlds[offx_r + q * 8 + ki * 32];
                bf16x8 bz = *(const bf16x8*)&wxlds[offx_z + q * 8 + ki * 32];
                bf16x8 bn = *(const bf16x8*)&wxlds[offx_n + q * 8 + ki * 32];
                ar  = __builtin_amdgcn_mfma_f32_16x16x32_bf16(a, br, ar, 0, 0, 0);
                az  = __builtin_amdgcn_mfma_f32_16x16x32_bf16(a, bz, az, 0, 0, 0);
                axn = __builtin_amdgcn_mfma_f32_16x16x32_bf16(a, bn, axn, 0, 0, 0);
            }
        }

        // ---- B: release h_t — ack is free now (stores are ~1.5us old) ----
        asm volatile("s_waitcnt vmcnt(0)" ::: "memory");
        __builtin_amdgcn_sched_barrier(0);
        if (l == 0)
            __hip_atomic_store(&flags[w * 64 + g], (unsigned)t,
                               __ATOMIC_RELAXED, __HIP_MEMORY_SCOPE_AGENT);

        // ---- C: poll this plane's 64 flags (one dword load per lane) ----
        {
            int spins = 0;
            for (;;) {
                unsigned v;
                asm volatile("global_load_dword %0, %1, off sc0 sc1" : "=v"(v) : "v"(fp));
                asm volatile("s_waitcnt vmcnt(0)" ::: "memory");
                __builtin_amdgcn_sched_barrier(0);
                if (__all(v >= (unsigned)t)) break;
                if (++spins > 12000) break;        // bounded: fail loud, don't hang
                if (spins < 64) { __builtin_amdgcn_s_sleep(1); }
                else            { __builtin_amdgcn_s_sleep(4); }
            }
        }

        // ---- D: certified burst (32 dwordx4/lane), counted-vmcnt drain ----
        {
            const unsigned short* hp = hbuf16 + (size_t)(t & 1) * HWORDS
                                     + batch_A * H_ + q * 8;
            u32x4 d[32];
            __builtin_amdgcn_sched_barrier(0);
            ISSUE_ALL();
            WAITV(24); mfma_group<0>(d, wr, wz, wn, ar, az, ahn);
            WAITV(16); mfma_group<1>(d, wr, wz, wn, ar, az, ahn);
            WAITV(8);  mfma_group<2>(d, wr, wz, wn, ar, az, ahn);
            WAITV(0);  mfma_group<3>(d, wr, wz, wn, ar, az, ahn);
        }

        // ---- E: gates ----
        float hnw[4];
        #pragma unroll
        for (int r = 0; r < 4; ++r) {
            float rr = __builtin_amdgcn_rcpf(1.0f + __expf(-ar[r]));
            float zz = __builtin_amdgcn_rcpf(1.0f + __expf(-az[r]));
            float narg = axn[r] + rr * ahn[r];
            float E = __expf(-2.0f * fabsf(narg));
            float nn = copysignf((1.0f - E) * __builtin_amdgcn_rcpf(1.0f + E), narg);
            float m = mc[r];
            float curr = (1.0f - zz) * nn + zz * hd[r];
            hnw[r] = m * curr + (1.0f - m) * hd[r];
        }

        // ---- F: store h_{t+1} (no ack — next iteration's B acks it), out(t) ----
        if (t < S_) {
            #pragma unroll
            for (int r = 0; r < 4; ++r) {
                hd[r] = hnw[r] * (dm[r] * mn[r] + 1.0f - mn[r]);   // pre-drop t+1
                mc[r] = mn[r];
                __hip_atomic_store(&hbuf16[(size_t)((t + 1) & 1) * HWORDS
                                           + batch_C[r] * H_ + jd],
                                   f2bf(hd[r]),
                                   __ATOMIC_RELAXED, __HIP_MEMORY_SCOPE_AGENT);
            }
            #pragma unroll
            for (int r = 0; r < 4; ++r)
                out[((size_t)batch_C[r] * S_ + s) * H_ + jd] = hnw[r];
        } else {
            #pragma unroll
            for (int r = 0; r < 4; ++r) {
                out[((size_t)batch_C[r] * S_ + s) * H_ + jd] = hnw[r];
                out_last[batch_C[r] * H_ + jd] = hnw[r];
            }
        }
        asm volatile("" ::: "memory");
    }
}

extern "C" void kernel_launch(void* const* d_in, const int* in_sizes, int n_in,
                              void* d_out, int out_size, void* d_ws, size_t ws_size,
                              hipStream_t stream) {
    (void)in_sizes; (void)n_in; (void)out_size; (void)ws_size;
    const float* x     = (const float*)d_in[0];
    const float* mask  = (const float*)d_in[1];
    const float* inith = (const float*)d_in[2];
    const float* dmask = (const float*)d_in[3];
    const float* Wih   = (const float*)d_in[4];
    const float* Whh   = (const float*)d_in[5];
    const float* bih   = (const float*)d_in[6];
    const float* bhh   = (const float*)d_in[7];
    float* out      = (float*)d_out;
    float* out_last = out + (size_t)B_ * S_ * H_;

    char* ws = (char*)d_ws;
    unsigned* flags       = (unsigned*)ws;                         // 1KB used, 8KB pad
    unsigned short* hbuf  = (unsigned short*)(ws + 8192);          // 256KB (2x h bf16)
    unsigned short* xbf   = (unsigned short*)(ws + 8192 + 262144); // 32MB

    (void)hipMemsetAsync(ws, 0, 8192, stream);                     // flags <- 0
    gru_prep<<<2048, 256, 0, stream>>>(x, xbf);
    gru_scan<<<NB, 256, 0, stream>>>(xbf, Wih, mask, inith, dmask, Whh, bih, bhh,
                                     out, out_last, flags, hbuf);
}